// Round 1
// baseline (147.915 us; speedup 1.0000x reference)
//
#include <hip/hip_runtime.h>

// QuadraticConv2DTranspose, stride 2, k=3.
// Key insight: bed-of-nails upsample => per output-pixel parity class only
// 1/2/2/4 patch values are nonzero; only 2/5/5/14 of the 55 features are
// live (plus a pixel-independent bias vector). 872M MACs instead of 7.4G.

namespace {
constexpr int kB = 8, kH = 32, kW = 32, kC = 64, kO = 64;
constexpr int kHO = 64, kWO = 64;
constexpr int kCC = 8;        // input-channel chunk
constexpr int kMaxNF = 14;    // OO class feature count
constexpr int kBiasL = 54;    // bias feature index
}

// Per-class tables. v ordering: value j comes from x[hi+DY[j], wi+DX[j]].
// Feature f has kernel l-index L[f] and value v[A[f]]*v[Bb[f]] (Bb==NV -> 1.0).
template <int CLS> struct CI;
template <> struct CI<0> {  // ho even, wo even
  static constexpr int NV = 1, NF = 2;
  static constexpr int L[NF] = {30, 49};
  static constexpr int A[NF] = {0, 0};
  static constexpr int Bb[NF] = {0, 1};
  static constexpr int DY[NV] = {0};
  static constexpr int DX[NV] = {0};
};
template <> struct CI<1> {  // ho even, wo odd
  static constexpr int NV = 2, NF = 5;
  static constexpr int L[NF] = {24, 26, 35, 48, 50};
  static constexpr int A[NF] = {0, 0, 1, 0, 1};
  static constexpr int Bb[NF] = {0, 1, 1, 2, 2};
  static constexpr int DY[NV] = {0, 0};
  static constexpr int DX[NV] = {0, 1};
};
template <> struct CI<2> {  // ho odd, wo even
  static constexpr int NV = 2, NF = 5;
  static constexpr int L[NF] = {9, 15, 42, 46, 52};
  static constexpr int A[NF] = {0, 0, 1, 0, 1};
  static constexpr int Bb[NF] = {0, 1, 1, 2, 2};
  static constexpr int DY[NV] = {0, 1};
  static constexpr int DX[NV] = {0, 0};
};
template <> struct CI<3> {  // ho odd, wo odd
  static constexpr int NV = 4, NF = 14;
  static constexpr int L[NF] = {0, 2, 6, 8, 17, 21, 23, 39, 41, 44, 45, 47, 51, 53};
  static constexpr int A[NF] = {0, 0, 0, 0, 1, 1, 1, 2, 2, 3, 0, 1, 2, 3};
  static constexpr int Bb[NF] = {0, 1, 2, 3, 1, 2, 3, 2, 3, 3, 4, 4, 4, 4};
  static constexpr int DY[NV] = {0, 0, 1, 1};
  static constexpr int DX[NV] = {0, 1, 0, 1};
};

__global__ __launch_bounds__(256) void bias_kernel(const float* __restrict__ kern,
                                                   float* __restrict__ bias) {
  __shared__ float sb[4][64];
  const int o = threadIdx.x & 63;
  const int part = threadIdx.x >> 6;
  float s = 0.f;
#pragma unroll
  for (int c = 0; c < 16; ++c)
    s += kern[(kBiasL * kC + part * 16 + c) * kO + o];
  sb[part][o] = s;
  __syncthreads();
  if (part == 0) bias[o] = sb[0][o] + sb[1][o] + sb[2][o] + sb[3][o];
}

template <int CLS>
__device__ __forceinline__ void body(const float* __restrict__ x,
                                     const float* __restrict__ kern,
                                     const float* __restrict__ bias,
                                     float* __restrict__ out, int b, int hi0,
                                     int wi0, float (&sX)[45][9],
                                     float (&sF)[kCC * kMaxNF][32],
                                     float (&sK)[kCC * kMaxNF][64]) {
  using I = CI<CLS>;
  constexpr int NV = I::NV, NF = I::NF;
  const int tid = threadIdx.x;
  const int to = tid & 15;   // cout group: o = 4*to .. 4*to+3
  const int tp = tid >> 4;   // pixel pair: p = 2*tp, 2*tp+1
  const int pF = tid & 31;   // feature phase: pixel
  const int cgF = tid >> 5;  // feature phase: channel within chunk
  const int phF = pF >> 2, pwF = pF & 3;

  float acc[2][4];
  {
    const float4 bv = *(const float4*)&bias[to * 4];
    acc[0][0] = bv.x; acc[0][1] = bv.y; acc[0][2] = bv.z; acc[0][3] = bv.w;
    acc[1][0] = bv.x; acc[1][1] = bv.y; acc[1][2] = bv.z; acc[1][3] = bv.w;
  }

  for (int c0 = 0; c0 < kC; c0 += kCC) {
    __syncthreads();  // protect LDS reuse vs previous chunk's GEMM reads
    // Stage x tile: 9 rows x 5 cols x 8 channels, zero-fill OOB (handles all
    // spatial boundary cases of the transpose-conv for free).
    for (int i = tid; i < 45 * 2; i += 256) {
      const int pos = i >> 1, half = i & 1;
      const int row = pos / 5, col = pos % 5;
      const int hr = hi0 + row, wc = wi0 + col;
      float4 v = make_float4(0.f, 0.f, 0.f, 0.f);
      if (hr < kH && wc < kW)
        v = *(const float4*)&x[(((b * kH) + hr) * kW + wc) * kC + c0 + half * 4];
      sX[pos][half * 4 + 0] = v.x;
      sX[pos][half * 4 + 1] = v.y;
      sX[pos][half * 4 + 2] = v.z;
      sX[pos][half * 4 + 3] = v.w;
    }
    // Stage gathered kernel slice: k = ci*NF + f rows of 64 couts.
    for (int i = tid; i < kCC * NF * 16; i += 256) {
      const int k = i >> 4, og = i & 15;
      const int ci = k / NF, f = k % NF;  // NF constexpr -> mul/shift
      const int l = I::L[f];
      *(float4*)&sK[k][og * 4] =
          *(const float4*)&kern[((l * kC) + c0 + ci) * kO + og * 4];
    }
    __syncthreads();
    // Materialize feature matrix F[k][pixel] in LDS.
    {
      float v[NV + 1];
#pragma unroll
      for (int j = 0; j < NV; ++j)
        v[j] = sX[(phF + I::DY[j]) * 5 + (pwF + I::DX[j])][cgF];
      v[NV] = 1.f;
#pragma unroll
      for (int f = 0; f < NF; ++f)
        sF[cgF * NF + f][pF] = v[I::A[f]] * v[I::Bb[f]];
    }
    __syncthreads();
    // Register-tiled GEMM: acc[2 pixels][4 couts] over k = ci*NF+f.
    for (int ci = 0; ci < kCC; ++ci) {
#pragma unroll
      for (int f = 0; f < NF; ++f) {
        const int k = ci * NF + f;
        const float2 fv = *(const float2*)&sF[k][tp * 2];
        const float4 kv = *(const float4*)&sK[k][to * 4];
        acc[0][0] = fmaf(fv.x, kv.x, acc[0][0]);
        acc[0][1] = fmaf(fv.x, kv.y, acc[0][1]);
        acc[0][2] = fmaf(fv.x, kv.z, acc[0][2]);
        acc[0][3] = fmaf(fv.x, kv.w, acc[0][3]);
        acc[1][0] = fmaf(fv.y, kv.x, acc[1][0]);
        acc[1][1] = fmaf(fv.y, kv.y, acc[1][1]);
        acc[1][2] = fmaf(fv.y, kv.z, acc[1][2]);
        acc[1][3] = fmaf(fv.y, kv.w, acc[1][3]);
      }
    }
  }

  // Epilogue: scatter to output (contiguous 256B per pixel across to-groups).
  constexpr int rh = CLS >> 1, rw = CLS & 1;
#pragma unroll
  for (int i = 0; i < 2; ++i) {
    const int p = tp * 2 + i;
    const int hi = hi0 + (p >> 2), wi = wi0 + (p & 3);
    const int ho = 2 * hi + rh, wo = 2 * wi + rw;
    *(float4*)&out[(((b * kHO) + ho) * kWO + wo) * kO + to * 4] =
        make_float4(acc[i][0], acc[i][1], acc[i][2], acc[i][3]);
  }
}

__global__ __launch_bounds__(256) void qct_main(const float* __restrict__ x,
                                                const float* __restrict__ kern,
                                                const float* __restrict__ bias,
                                                float* __restrict__ out) {
  __shared__ float sX[45][9];                 // 1.6 KB, +1 pad vs 8 -> conflict-free
  __shared__ float sF[kCC * kMaxNF][32];      // 14.3 KB
  __shared__ float sK[kCC * kMaxNF][64];      // 28.7 KB
  const int cls = blockIdx.x & 3;
  const int blk = blockIdx.x >> 2;
  const int b = blk >> 5;
  const int tile = blk & 31;
  const int hi0 = (tile >> 3) * 8;  // 8x4 class-space tile = 32 pixels
  const int wi0 = (tile & 7) * 4;
  switch (cls) {
    case 0: body<0>(x, kern, bias, out, b, hi0, wi0, sX, sF, sK); break;
    case 1: body<1>(x, kern, bias, out, b, hi0, wi0, sX, sF, sK); break;
    case 2: body<2>(x, kern, bias, out, b, hi0, wi0, sX, sF, sK); break;
    case 3: body<3>(x, kern, bias, out, b, hi0, wi0, sX, sF, sK); break;
  }
}

extern "C" void kernel_launch(void* const* d_in, const int* in_sizes, int n_in,
                              void* d_out, int out_size, void* d_ws,
                              size_t ws_size, hipStream_t stream) {
  const float* x = (const float*)d_in[0];       // [8,32,32,64] f32
  const float* kern = (const float*)d_in[1];    // [55,64,64]  f32
  float* out = (float*)d_out;                   // [8,64,64,64] f32
  float* bias = (float*)d_ws;                   // 64 floats scratch

  bias_kernel<<<1, 256, 0, stream>>>(kern, bias);
  // 4 classes x 8 images x 32 tiles = 1024 blocks -> dynamic balance of the
  // 7:1 per-class work ratio across 256 CUs (~3 blocks/CU LDS-limited).
  qct_main<<<1024, 256, 0, stream>>>(x, kern, bias, out);
}

// Round 2
// 73.673 us; speedup vs baseline: 2.0077x; 2.0077x over previous
//
#include <hip/hip_runtime.h>
#include <stdint.h>

// QuadraticConv2DTranspose via per-parity-class bf16 MFMA GEMM.
// Bed-of-nails stride-2 upsample => per output-parity class only 2/5/5/14 of
// the 55 features are live (+ pixel-independent bias). Cast as 4 GEMMs:
//   out[m,n] = bias[n] + sum_k F[m,k] * W[k,n],  k = f*64 + c
// M=8192 pixels/class, N=64, K=64*NF. A-frags built in registers from cached
// patch planes (zero LDS traffic for A in the K-loop); W transposed to
// sBt[n][k] bf16 in LDS (double-buffered, 1 barrier/feature).

namespace {
constexpr int kBiasL = 54;
}

typedef __attribute__((ext_vector_type(8))) short short8;
typedef __attribute__((ext_vector_type(4))) float floatx4;

__device__ __forceinline__ short f2bf(float f) {  // RTN-even fp32->bf16
  union { float f; uint32_t u; } v{f};
  uint32_t u = v.u;
  u += 0x7fffu + ((u >> 16) & 1u);
  return (short)(u >> 16);
}

// Per-class tables. Patch value j = x[hi+DY[j], wi+DX[j]].
// Feature f: kernel row L[f], value v[A[f]]*v[Bb[f]]; Bb[f]==NV -> linear (v[A]).
template <int CLS> struct CI;
template <> struct CI<0> {  // ho even, wo even
  static constexpr int NV = 1, NF = 2;
  static constexpr int L[NF] = {30, 49};
  static constexpr int A[NF] = {0, 0};
  static constexpr int Bb[NF] = {0, 1};
  static constexpr int DY[NV] = {0};
  static constexpr int DX[NV] = {0};
};
template <> struct CI<1> {  // ho even, wo odd
  static constexpr int NV = 2, NF = 5;
  static constexpr int L[NF] = {24, 26, 35, 48, 50};
  static constexpr int A[NF] = {0, 0, 1, 0, 1};
  static constexpr int Bb[NF] = {0, 1, 1, 2, 2};
  static constexpr int DY[NV] = {0, 0};
  static constexpr int DX[NV] = {0, 1};
};
template <> struct CI<2> {  // ho odd, wo even
  static constexpr int NV = 2, NF = 5;
  static constexpr int L[NF] = {9, 15, 42, 46, 52};
  static constexpr int A[NF] = {0, 0, 1, 0, 1};
  static constexpr int Bb[NF] = {0, 1, 1, 2, 2};
  static constexpr int DY[NV] = {0, 1};
  static constexpr int DX[NV] = {0, 0};
};
template <> struct CI<3> {  // ho odd, wo odd
  static constexpr int NV = 4, NF = 14;
  static constexpr int L[NF] = {0, 2, 6, 8, 17, 21, 23, 39, 41, 44, 45, 47, 51, 53};
  static constexpr int A[NF] = {0, 0, 0, 0, 1, 1, 1, 2, 2, 3, 0, 1, 2, 3};
  static constexpr int Bb[NF] = {0, 1, 2, 3, 1, 2, 3, 2, 3, 3, 4, 4, 4, 4};
  static constexpr int DY[NV] = {0, 0, 1, 1};
  static constexpr int DX[NV] = {0, 1, 0, 1};
};

__global__ __launch_bounds__(256) void bias_kernel(const float* __restrict__ kern,
                                                   float* __restrict__ bias) {
  __shared__ float sb[4][64];
  const int o = threadIdx.x & 63;
  const int part = threadIdx.x >> 6;
  float s = 0.f;
#pragma unroll
  for (int c = 0; c < 16; ++c)
    s += kern[(kBiasL * 64 + part * 16 + c) * 64 + o];
  sb[part][o] = s;
  __syncthreads();
  if (part == 0) bias[o] = sb[0][o] + sb[1][o] + sb[2][o] + sb[3][o];
}

template <int CLS>
__device__ __forceinline__ void body(const float* __restrict__ x,
                                     const float* __restrict__ kern,
                                     const float* __restrict__ bias,
                                     float* __restrict__ out, int b, int hi0,
                                     int wi0, float (&sX)[45][36],
                                     short (&sBt)[2][64][40]) {
  using I = CI<CLS>;
  constexpr int NV = I::NV, NF = I::NF;
  const int tid = threadIdx.x;
  const int wave = tid >> 6, lane = tid & 63;
  const int quad = lane >> 4, l16 = lane & 15;
  const int mb = (wave & 1) * 16;   // wave's m-block (pixels)
  const int nh = (wave >> 1) * 32;  // wave's n-half (couts)
  const int m = mb + l16;           // A-operand row: m = lane&15
  const int ph = m >> 3, pw = m & 7;
  const int c8 = quad * 8;          // A/B k-offset: k = quad*8 + j

  floatx4 acc[2];
#pragma unroll
  for (int nt = 0; nt < 2; ++nt) {  // C/D col = lane&15 -> same bias all rows
    const float bv = bias[nh + nt * 16 + l16];
    acc[nt] = floatx4{bv, bv, bv, bv};
  }

  int fidx = 0;
  for (int chalf = 0; chalf < 2; ++chalf) {
    const int c0 = chalf * 32;
    // Stage x tile (5x9 positions, 32 channels, fp32, zero OOB). Row pad to
    // 36 floats (144 B) keeps b128 alignment, breaks bank aliasing.
    for (int i = tid; i < 45 * 8; i += 256) {
      const int pos = i >> 3, c4 = (i & 7) * 4;
      const int hr = hi0 + pos / 9, wc = wi0 + pos % 9;
      float4 v = make_float4(0.f, 0.f, 0.f, 0.f);
      if (hr < 32 && wc < 32)
        v = *(const float4*)&x[(((b * 32) + hr) * 32 + wc) * 64 + c0 + c4];
      *(float4*)&sX[pos][c4] = v;
    }
    __syncthreads();
    // Cache this lane's patch planes (8 channels each) in registers.
    float vpl[NV][8];
#pragma unroll
    for (int j = 0; j < NV; ++j) {
      const int pa = (ph + I::DY[j]) * 9 + (pw + I::DX[j]);
      *(float4*)&vpl[j][0] = *(const float4*)&sX[pa][c8];
      *(float4*)&vpl[j][4] = *(const float4*)&sX[pa][c8 + 4];
    }
    for (int f = 0; f < NF; ++f, ++fidx) {
      short(&sB)[64][40] = sBt[fidx & 1];  // dbuf -> 1 barrier per feature
      {  // Stage W[c0+kk][n] -> sBt[n][kk] bf16. Lane owns column n, wave
         // owns 8 kk rows: 8 coalesced dword loads -> one ds_write_b128.
        const int n = tid & 63, kkg = (tid >> 6) * 8;
        const float* src = &kern[((I::L[f] * 64) + c0 + kkg) * 64 + n];
        short8 wv;
#pragma unroll
        for (int j = 0; j < 8; ++j) wv[j] = f2bf(src[j * 64]);
        *(short8*)&sB[n][kkg] = wv;
      }
      __syncthreads();
      // A-frag from cached planes: zero LDS traffic.
      short8 afrag;
#pragma unroll
      for (int j = 0; j < 8; ++j) {
        const float v = (I::Bb[f] == NV) ? vpl[I::A[f]][j]
                                         : vpl[I::A[f]][j] * vpl[I::Bb[f]][j];
        afrag[j] = f2bf(v);
      }
#pragma unroll
      for (int nt = 0; nt < 2; ++nt) {
        const short8 bfrag = *(const short8*)&sB[nh + nt * 16 + l16][c8];
        acc[nt] =
            __builtin_amdgcn_mfma_f32_16x16x32_bf16(afrag, bfrag, acc[nt], 0, 0, 0);
      }
      // no trailing barrier: next f stages the other sBt buffer; sX re-stage
      // next chalf is ordered by this chalf's last per-f barrier.
    }
  }

  // Epilogue. D: col = n = lane&15 group, row = quad*4 + reg.
  constexpr int rh = CLS >> 1, rw = CLS & 1;
#pragma unroll
  for (int nt = 0; nt < 2; ++nt) {
    const int n = nh + nt * 16 + l16;
#pragma unroll
    for (int r = 0; r < 4; ++r) {
      const int mm = mb + quad * 4 + r;
      const int hi = hi0 + (mm >> 3), wi = wi0 + (mm & 7);
      const int ho = 2 * hi + rh, wo = 2 * wi + rw;
      out[(((b * 64) + ho) * 64 + wo) * 64 + n] = acc[nt][r];
    }
  }
}

__global__ __launch_bounds__(256) void qct_main(const float* __restrict__ x,
                                                const float* __restrict__ kern,
                                                const float* __restrict__ bias,
                                                float* __restrict__ out) {
  __shared__ float sX[45][36];       // 6.5 KB
  __shared__ short sBt[2][64][40];   // 10 KB (double-buffered W slice)
  const int bid = blockIdx.x;
  // OO first: longest-job-first across CUs (7:1 per-class work ratio).
  int cls, blk;
  if (bid < 256)      { cls = 3; blk = bid; }
  else if (bid < 512) { cls = 1; blk = bid - 256; }
  else if (bid < 768) { cls = 2; blk = bid - 512; }
  else                { cls = 0; blk = bid - 768; }
  const int b = blk >> 5, tile = blk & 31;
  const int hi0 = (tile >> 2) * 4;  // 4x8 class-space tile = 32 pixels
  const int wi0 = (tile & 3) * 8;
  switch (cls) {
    case 0: body<0>(x, kern, bias, out, b, hi0, wi0, sX, sBt); break;
    case 1: body<1>(x, kern, bias, out, b, hi0, wi0, sX, sBt); break;
    case 2: body<2>(x, kern, bias, out, b, hi0, wi0, sX, sBt); break;
    case 3: body<3>(x, kern, bias, out, b, hi0, wi0, sX, sBt); break;
  }
}

extern "C" void kernel_launch(void* const* d_in, const int* in_sizes, int n_in,
                              void* d_out, int out_size, void* d_ws,
                              size_t ws_size, hipStream_t stream) {
  const float* x = (const float*)d_in[0];     // [8,32,32,64] f32
  const float* kern = (const float*)d_in[1];  // [55,64,64]   f32
  float* out = (float*)d_out;                 // [8,64,64,64] f32
  float* bias = (float*)d_ws;                 // 64 floats scratch

  bias_kernel<<<1, 256, 0, stream>>>(kern, bias);
  // 1024 blocks = 4 classes x 256; ~4 blocks/CU for latency hiding.
  qct_main<<<1024, 256, 0, stream>>>(x, kern, bias, out);
}